// Round 1
// 395.472 us; speedup vs baseline: 1.0395x; 1.0395x over previous
//
#include <hip/hip_runtime.h>
#include <stdint.h>

#define IN_F   4096
#define OUT_F  4096
#define TOKENS 8192
#define RANK   16

#define BM 128
#define BN 128
#define BKI 64   // i8 K-tile (16x16x64 MFMA)

typedef unsigned short u16;
typedef __attribute__((ext_vector_type(8))) short bf16x8;
typedef __attribute__((ext_vector_type(4))) float f32x4;
typedef __attribute__((ext_vector_type(4))) int i32x4;

// async global->LDS, 16B/lane; LDS dest = wave-uniform base, HW adds lane*16
#define GLDS16(g, l) __builtin_amdgcn_global_load_lds( \
    (__attribute__((address_space(1))) void*)(g),      \
    (__attribute__((address_space(3))) void*)(l), 16, 0, 0)

// LDS slot swizzle for 64B rows read as 4x16B slots:
// slot' = slot ^ (row&3) ^ ((row>>2)&1). Within a 16-lane fragment-read group
// (rows r..r+15, fixed k-slot) every bank-quad is hit exactly 2x (free).
__device__ __forceinline__ int swz_row(int row) {
    return (row & 3) ^ ((row >> 2) & 1);
}

__device__ __forceinline__ u16 bf16bits(float f) {
    unsigned int u = __builtin_bit_cast(unsigned int, f);
    unsigned int lsb = (u >> 16) & 1u;
    u += 0x7fffu + lsb;
    return (u16)(u >> 16);
}

__device__ __forceinline__ unsigned int quant4(float a, float b, float c, float d, float inv) {
    int qa = __float2int_rn(a * inv); qa = max(-127, min(127, qa));
    int qb = __float2int_rn(b * inv); qb = max(-127, min(127, qb));
    int qc = __float2int_rn(c * inv); qc = max(-127, min(127, qc));
    int qd = __float2int_rn(d * inv); qd = max(-127, min(127, qd));
    return (qa & 255) | ((qb & 255) << 8) | ((qc & 255) << 16) | ((qd & 255) << 24);
}

// ---- fused prep: [0,TOKENS) token quant | next 4096 W-build | next 16 B-lora | last 16 A-quant
__global__ __launch_bounds__(256) void k_prep(const float* __restrict__ X,
                                              const int* __restrict__ packed,
                                              const float* __restrict__ lA,
                                              const float* __restrict__ lB,
                                              signed char* __restrict__ Xq,
                                              float* __restrict__ sArr,
                                              float* __restrict__ SArr,
                                              signed char* __restrict__ Wq,
                                              u16* __restrict__ Bl,
                                              signed char* __restrict__ Aq,
                                              float* __restrict__ aScale) {
    __shared__ float rs[4], rm[4];
    const int b = blockIdx.x;
    const int tid = threadIdx.x;
    const int lane = tid & 63;
    const int wv = tid >> 6;

    if (b < TOKENS) {
        // ---- per-token absmax/sum + int8 quantize ----
        const int t = b;
        const float4* X4 = (const float4*)(X + (size_t)t * IN_F);
        float4 v[4];
#pragma unroll
        for (int j = 0; j < 4; j++) v[j] = X4[tid * 4 + j];

        float s = 0.f, m = 0.f;
#pragma unroll
        for (int j = 0; j < 4; j++) {
            s += v[j].x + v[j].y + v[j].z + v[j].w;
            m = fmaxf(m, fmaxf(fmaxf(fabsf(v[j].x), fabsf(v[j].y)),
                               fmaxf(fabsf(v[j].z), fabsf(v[j].w))));
        }
#pragma unroll
        for (int off = 32; off > 0; off >>= 1) {
            s += __shfl_down(s, off);
            m = fmaxf(m, __shfl_down(m, off));
        }
        if (lane == 0) { rs[wv] = s; rm[wv] = m; }
        __syncthreads();
        float S = rs[0] + rs[1] + rs[2] + rs[3];
        float M = fmaxf(fmaxf(rm[0], rm[1]), fmaxf(rm[2], rm[3]));
        M = fmaxf(M, 1e-20f);
        if (tid == 0) { SArr[t] = S; sArr[t] = M / 127.0f; }

        float inv = 127.0f / M;
        uint4 o;
        o.x = quant4(v[0].x, v[0].y, v[0].z, v[0].w, inv);
        o.y = quant4(v[1].x, v[1].y, v[1].z, v[1].w, inv);
        o.z = quant4(v[2].x, v[2].y, v[2].z, v[2].w, inv);
        o.w = quant4(v[3].x, v[3].y, v[3].z, v[3].w, inv);
        *(uint4*)(Xq + (size_t)t * IN_F + tid * 16) = o;
    } else if (b < TOKENS + OUT_F * (IN_F / 16) / 256) {
        // ---- W ternary -> int8 ----
        int idx = (b - TOKENS) * 256 + tid;  // [0, OUT_F*WORDS)
        int p = packed[idx];
        uint4 o;
        unsigned int w[4];
#pragma unroll
        for (int g = 0; g < 4; g++) {
            unsigned int word = 0;
#pragma unroll
            for (int j = 0; j < 4; j++) {
                int k = g * 4 + j;
                int bb = ((p >> (2 * k)) & 3) - 1;
                word |= (unsigned int)(bb & 255) << (8 * j);
            }
            w[g] = word;
        }
        o.x = w[0]; o.y = w[1]; o.z = w[2]; o.w = w[3];
        *(uint4*)(Wq + (size_t)idx * 16) = o;
    } else if (b < TOKENS + OUT_F * (IN_F / 16) / 256 + OUT_F / 256) {
        // ---- B lora -> bf16 zero-padded to K=32 ----
        int o = (b - TOKENS - OUT_F * (IN_F / 16) / 256) * 256 + tid;  // [0, OUT_F)
        const float4* B4 = (const float4*)(lB + (size_t)o * RANK);
        float4 b0 = B4[0], b1 = B4[1], b2 = B4[2], b3 = B4[3];
        union { u16 u[32]; uint4 q[4]; } ob;
        ob.u[0] = bf16bits(b0.x); ob.u[1] = bf16bits(b0.y); ob.u[2] = bf16bits(b0.z); ob.u[3] = bf16bits(b0.w);
        ob.u[4] = bf16bits(b1.x); ob.u[5] = bf16bits(b1.y); ob.u[6] = bf16bits(b1.z); ob.u[7] = bf16bits(b1.w);
        ob.u[8] = bf16bits(b2.x); ob.u[9] = bf16bits(b2.y); ob.u[10] = bf16bits(b2.z); ob.u[11] = bf16bits(b2.w);
        ob.u[12] = bf16bits(b3.x); ob.u[13] = bf16bits(b3.y); ob.u[14] = bf16bits(b3.z); ob.u[15] = bf16bits(b3.w);
#pragma unroll
        for (int k = 16; k < 32; k++) ob.u[k] = 0;
        uint4* dst = (uint4*)(Bl + (size_t)o * 32);
        dst[0] = ob.q[0]; dst[1] = ob.q[1]; dst[2] = ob.q[2]; dst[3] = ob.q[3];
    } else {
        // ---- quantize lora_A rows to int8 (per-row scale) ----
        const int r = b - (TOKENS + OUT_F * (IN_F / 16) / 256 + OUT_F / 256);
        const float4* A4 = (const float4*)(lA + (size_t)r * IN_F);
        float4 v[4];
#pragma unroll
        for (int j = 0; j < 4; j++) v[j] = A4[tid * 4 + j];

        float m = 0.f;
#pragma unroll
        for (int j = 0; j < 4; j++)
            m = fmaxf(m, fmaxf(fmaxf(fabsf(v[j].x), fabsf(v[j].y)),
                               fmaxf(fabsf(v[j].z), fabsf(v[j].w))));
#pragma unroll
        for (int off = 32; off > 0; off >>= 1) m = fmaxf(m, __shfl_down(m, off));
        if (lane == 0) rm[wv] = m;
        __syncthreads();
        float M = fmaxf(fmaxf(rm[0], rm[1]), fmaxf(rm[2], rm[3]));
        M = fmaxf(M, 1e-20f);
        if (tid == 0) aScale[r] = M / 127.0f;

        float inv = 127.0f / M;
        uint4 o;
        o.x = quant4(v[0].x, v[0].y, v[0].z, v[0].w, inv);
        o.y = quant4(v[1].x, v[1].y, v[1].z, v[1].w, inv);
        o.z = quant4(v[2].x, v[2].y, v[2].z, v[2].w, inv);
        o.w = quant4(v[3].x, v[3].y, v[3].z, v[3].w, inv);
        *(uint4*)(Aq + (size_t)r * IN_F + tid * 16) = o;
    }
}

// ---- y = x * A^T via i8 MFMA: 16 tokens per block, 4 waves K-split + LDS reduce ----
__global__ __launch_bounds__(256) void k_lora_y(const signed char* __restrict__ Xq,
                                                const signed char* __restrict__ Aq,
                                                const float* __restrict__ sArr,
                                                const float* __restrict__ aScale,
                                                u16* __restrict__ ypad) {
    __shared__ i32x4 red[4][64];
    const int tid = threadIdx.x;
    const int lane = tid & 63;
    const int wv = tid >> 6;
    const int t0 = blockIdx.x * 16;
    const int fr = lane & 15;
    const int q16 = (lane >> 4) * 16;

    i32x4 acc = {};
    const signed char* xrow = Xq + (size_t)(t0 + fr) * IN_F + wv * 1024 + q16;
    const signed char* arow = Aq + (size_t)fr * IN_F + wv * 1024 + q16;
#pragma unroll
    for (int k0 = 0; k0 < 1024; k0 += BKI) {
        i32x4 af = *(const i32x4*)(xrow + k0);
        i32x4 bf = *(const i32x4*)(arow + k0);
        acc = __builtin_amdgcn_mfma_i32_16x16x64_i8(af, bf, acc, 0, 0, 0);
    }
    red[wv][lane] = acc;
    __syncthreads();
    if (wv == 0) {
        i32x4 s0 = red[0][lane], s1 = red[1][lane], s2 = red[2][lane], s3 = red[3][lane];
        const int c0 = lane & 15;          // rank
        const int r0 = (lane >> 4) * 4;    // token within group
        float asc = aScale[c0];
#pragma unroll
        for (int r = 0; r < 4; r++) {
            int t = t0 + r0 + r;
            float y = sArr[t] * asc * (float)(s0[r] + s1[r] + s2[r] + s3[r]);
            ypad[(size_t)t * 32 + c0] = bf16bits(y);
            ypad[(size_t)t * 32 + 16 + c0] = 0;
        }
    }
}

// ---- main int8 GEMM + fused epilogue (scale, mu, bias, lora MFMA) ----
__global__ __launch_bounds__(256, 2) void k_gemm_i8(const signed char* __restrict__ Xq,
                                                    const signed char* __restrict__ Wq,
                                                    const float* __restrict__ sArr,
                                                    const float* __restrict__ SArr,
                                                    const float* __restrict__ alpha,
                                                    const float* __restrict__ mu,
                                                    const float* __restrict__ bias,
                                                    const u16* __restrict__ ypad,
                                                    const u16* __restrict__ Bl,
                                                    float* __restrict__ out) {
    __shared__ unsigned char smem[16384];
    unsigned char* smA = smem;
    unsigned char* smB = smem + 8192;

    const int tid = threadIdx.x;
    const int lane = tid & 63;
    const int wv = tid >> 6;
    const int wm = (wv >> 1) * 64;
    const int wn = (wv & 1) * 64;
    const int fr = lane & 15;
    const int qs = lane >> 4;                       // k-slot 0..3 (16B units)
    const int sw = swz_row(fr);                     // read-side swizzle (row&3 == fr&3 etc.)
    const int rdoff = ((qs ^ sw) << 4);             // swizzled 16B slot within 64B row
    const int wvbase = wv * 1024;

    const int m0 = blockIdx.y * BM;
    const int n0 = blockIdx.x * BN;

    // staging geometry: c = i*256+tid; LDS byte c*16 holds (row=c>>2, slot=c&3);
    // source slot is XOR-swizzled so linear-dest LDS ends up swizzled (rule 21).
    int srow[2], soff[2];
#pragma unroll
    for (int i = 0; i < 2; i++) {
        int c = i * 256 + tid;
        srow[i] = c >> 2;
        soff[i] = (((c & 3) ^ swz_row(c >> 2)) << 4);
    }

    i32x4 acc[4][4] = {};

    for (int k0 = 0; k0 < IN_F; k0 += BKI) {
        __syncthreads();
#pragma unroll
        for (int i = 0; i < 2; i++)
            GLDS16(Xq + (size_t)(m0 + srow[i]) * IN_F + k0 + soff[i], smA + i * 4096 + wvbase);
#pragma unroll
        for (int i = 0; i < 2; i++)
            GLDS16(Wq + (size_t)(n0 + srow[i]) * IN_F + k0 + soff[i], smB + i * 4096 + wvbase);
        __syncthreads();

        i32x4 af[4], bf[4];
#pragma unroll
        for (int mt = 0; mt < 4; mt++)
            af[mt] = *(const i32x4*)(smA + (wm + mt * 16 + fr) * BKI + rdoff);
#pragma unroll
        for (int nt = 0; nt < 4; nt++)
            bf[nt] = *(const i32x4*)(smB + (wn + nt * 16 + fr) * BKI + rdoff);
#pragma unroll
        for (int mt = 0; mt < 4; mt++)
#pragma unroll
            for (int nt = 0; nt < 4; nt++)
                acc[mt][nt] = __builtin_amdgcn_mfma_i32_16x16x64_i8(af[mt], bf[nt], acc[mt][nt], 0, 0, 0);
    }

    // epilogue: convert int acc -> float with alpha*s, add mu*S + bias
    const int r0 = (lane >> 4) * 4;
    const int c0 = lane & 15;
    f32x4 facc[4][4];
#pragma unroll
    for (int mt = 0; mt < 4; mt++) {
        int rb = m0 + wm + mt * 16 + r0;
        f32x4 sv = *(const f32x4*)(sArr + rb);
        f32x4 Sv = *(const f32x4*)(SArr + rb);
#pragma unroll
        for (int nt = 0; nt < 4; nt++) {
            int col = n0 + wn + nt * 16 + c0;
            float av = alpha[col], mv = mu[col], bv = bias[col];
#pragma unroll
            for (int r = 0; r < 4; r++)
                facc[mt][nt][r] = av * sv[r] * (float)acc[mt][nt][r] + fmaf(mv, Sv[r], bv);
        }
    }

    // lora: one bf16 MFMA pass, C = facc (same swizzled staging, rows are 64B)
    __syncthreads();
#pragma unroll
    for (int i = 0; i < 2; i++) {
        GLDS16((const unsigned char*)ypad + (size_t)(m0 + srow[i]) * 64 + soff[i], smA + i * 4096 + wvbase);
        GLDS16((const unsigned char*)Bl + (size_t)(n0 + srow[i]) * 64 + soff[i], smB + i * 4096 + wvbase);
    }
    __syncthreads();
    bf16x8 yf[4], blf[4];
#pragma unroll
    for (int mt = 0; mt < 4; mt++)
        yf[mt] = *(const bf16x8*)(smA + (wm + mt * 16 + fr) * 64 + rdoff);
#pragma unroll
    for (int nt = 0; nt < 4; nt++)
        blf[nt] = *(const bf16x8*)(smB + (wn + nt * 16 + fr) * 64 + rdoff);
#pragma unroll
    for (int mt = 0; mt < 4; mt++)
#pragma unroll
        for (int nt = 0; nt < 4; nt++)
            facc[mt][nt] = __builtin_amdgcn_mfma_f32_16x16x32_bf16(yf[mt], blf[nt], facc[mt][nt], 0, 0, 0);

    // store
#pragma unroll
    for (int nt = 0; nt < 4; nt++) {
        int col = n0 + wn + nt * 16 + c0;
#pragma unroll
        for (int mt = 0; mt < 4; mt++) {
            int row = m0 + wm + mt * 16 + r0;
            float* op = out + (size_t)row * OUT_F + col;
#pragma unroll
            for (int r = 0; r < 4; r++)
                op[(size_t)r * OUT_F] = facc[mt][nt][r];
        }
    }
}

extern "C" void kernel_launch(void* const* d_in, const int* in_sizes, int n_in,
                              void* d_out, int out_size, void* d_ws, size_t ws_size,
                              hipStream_t stream) {
    const float* x      = (const float*)d_in[0];
    const int*   packed = (const int*)d_in[1];
    const float* alpha  = (const float*)d_in[2];
    const float* mu     = (const float*)d_in[3];
    const float* bias   = (const float*)d_in[4];
    const float* lA     = (const float*)d_in[5];
    const float* lB     = (const float*)d_in[6];
    float* out = (float*)d_out;

    char* p = (char*)d_ws;
    signed char* Wq = (signed char*)p;             p += (size_t)OUT_F * IN_F;        // 16 MiB
    signed char* Xq = (signed char*)p;             p += (size_t)TOKENS * IN_F;       // 32 MiB
    float* sArr = (float*)p;                       p += (size_t)TOKENS * 4;
    float* SArr = (float*)p;                       p += (size_t)TOKENS * 4;
    u16* ypad = (u16*)p;                           p += (size_t)TOKENS * 32 * 2;     // 512 KiB
    u16* Bl = (u16*)p;                             p += (size_t)OUT_F * 32 * 2;      // 256 KiB
    signed char* Aq = (signed char*)p;             p += (size_t)RANK * IN_F;         // 64 KiB
    float* aScale = (float*)p;                     p += RANK * 4;

    const int prep_blocks = TOKENS + OUT_F * (IN_F / 16) / 256 + OUT_F / 256 + RANK; // 12320
    k_prep<<<dim3(prep_blocks), dim3(256), 0, stream>>>(x, packed, lA, lB, Xq, sArr, SArr, Wq, Bl, Aq, aScale);
    k_lora_y<<<dim3(TOKENS / 16), dim3(256), 0, stream>>>(Xq, Aq, sArr, aScale, ypad);

    dim3 grid(OUT_F / BN, TOKENS / BM);  // (32, 64)
    k_gemm_i8<<<grid, dim3(256), 0, stream>>>(Xq, Wq, sArr, SArr, alpha, mu, bias, ypad, Bl, out);
}

// Round 2
// 363.447 us; speedup vs baseline: 1.1311x; 1.0881x over previous
//
#include <hip/hip_runtime.h>
#include <stdint.h>

#define IN_F   4096
#define OUT_F  4096
#define TOKENS 8192
#define RANK   16

#define BM 256
#define BN 256
#define BK 128            // i8 elements per K-tile = 128B rows
#define NT (IN_F / BK)    // 32 K-tiles

typedef unsigned short u16;
typedef __attribute__((ext_vector_type(8))) short bf16x8;
typedef __attribute__((ext_vector_type(4))) float f32x4;
typedef __attribute__((ext_vector_type(4))) int i32x4;

// async global->LDS, 16B/lane; LDS dest = wave-uniform base, HW adds lane*16
#define GLDS16(g, l) __builtin_amdgcn_global_load_lds( \
    (__attribute__((address_space(1))) void*)(g),      \
    (__attribute__((address_space(3))) void*)(l), 16, 0, 0)

#define MEMFENCE asm volatile("" ::: "memory")
#define BARRIER  do { MEMFENCE; __builtin_amdgcn_s_barrier(); MEMFENCE; } while (0)
#define VMCNT8   asm volatile("s_waitcnt vmcnt(8)" ::: "memory")
#define VMCNT0   asm volatile("s_waitcnt vmcnt(0)" ::: "memory")

__device__ __forceinline__ int swz4(int row) { return (row & 3) ^ ((row >> 2) & 1); }

__device__ __forceinline__ u16 bf16bits(float f) {
    unsigned int u = __builtin_bit_cast(unsigned int, f);
    unsigned int lsb = (u >> 16) & 1u;
    u += 0x7fffu + lsb;
    return (u16)(u >> 16);
}

__device__ __forceinline__ unsigned int quant4(float a, float b, float c, float d, float inv) {
    int qa = __float2int_rn(a * inv); qa = max(-127, min(127, qa));
    int qb = __float2int_rn(b * inv); qb = max(-127, min(127, qb));
    int qc = __float2int_rn(c * inv); qc = max(-127, min(127, qc));
    int qd = __float2int_rn(d * inv); qd = max(-127, min(127, qd));
    return (qa & 255) | ((qb & 255) << 8) | ((qc & 255) << 16) | ((qd & 255) << 24);
}

// ---- fused prep: [0,TOKENS) token quant | next 4096 W-build | next 16 B-lora | last 16 A-quant
__global__ __launch_bounds__(256) void k_prep(const float* __restrict__ X,
                                              const int* __restrict__ packed,
                                              const float* __restrict__ lA,
                                              const float* __restrict__ lB,
                                              signed char* __restrict__ Xq,
                                              float* __restrict__ sArr,
                                              float* __restrict__ SArr,
                                              signed char* __restrict__ Wq,
                                              u16* __restrict__ Bl,
                                              signed char* __restrict__ Aq,
                                              float* __restrict__ aScale) {
    __shared__ float rs[4], rm[4];
    const int b = blockIdx.x;
    const int tid = threadIdx.x;
    const int lane = tid & 63;
    const int wv = tid >> 6;

    if (b < TOKENS) {
        const int t = b;
        const float4* X4 = (const float4*)(X + (size_t)t * IN_F);
        float4 v[4];
#pragma unroll
        for (int j = 0; j < 4; j++) v[j] = X4[tid * 4 + j];

        float s = 0.f, m = 0.f;
#pragma unroll
        for (int j = 0; j < 4; j++) {
            s += v[j].x + v[j].y + v[j].z + v[j].w;
            m = fmaxf(m, fmaxf(fmaxf(fabsf(v[j].x), fabsf(v[j].y)),
                               fmaxf(fabsf(v[j].z), fabsf(v[j].w))));
        }
#pragma unroll
        for (int off = 32; off > 0; off >>= 1) {
            s += __shfl_down(s, off);
            m = fmaxf(m, __shfl_down(m, off));
        }
        if (lane == 0) { rs[wv] = s; rm[wv] = m; }
        __syncthreads();
        float S = rs[0] + rs[1] + rs[2] + rs[3];
        float M = fmaxf(fmaxf(rm[0], rm[1]), fmaxf(rm[2], rm[3]));
        M = fmaxf(M, 1e-20f);
        if (tid == 0) { SArr[t] = S; sArr[t] = M / 127.0f; }

        float inv = 127.0f / M;
        uint4 o;
        o.x = quant4(v[0].x, v[0].y, v[0].z, v[0].w, inv);
        o.y = quant4(v[1].x, v[1].y, v[1].z, v[1].w, inv);
        o.z = quant4(v[2].x, v[2].y, v[2].z, v[2].w, inv);
        o.w = quant4(v[3].x, v[3].y, v[3].z, v[3].w, inv);
        *(uint4*)(Xq + (size_t)t * IN_F + tid * 16) = o;
    } else if (b < TOKENS + OUT_F * (IN_F / 16) / 256) {
        int idx = (b - TOKENS) * 256 + tid;
        int p = packed[idx];
        uint4 o;
        unsigned int w[4];
#pragma unroll
        for (int g = 0; g < 4; g++) {
            unsigned int word = 0;
#pragma unroll
            for (int j = 0; j < 4; j++) {
                int k = g * 4 + j;
                int bb = ((p >> (2 * k)) & 3) - 1;
                word |= (unsigned int)(bb & 255) << (8 * j);
            }
            w[g] = word;
        }
        o.x = w[0]; o.y = w[1]; o.z = w[2]; o.w = w[3];
        *(uint4*)(Wq + (size_t)idx * 16) = o;
    } else if (b < TOKENS + OUT_F * (IN_F / 16) / 256 + OUT_F / 256) {
        int o = (b - TOKENS - OUT_F * (IN_F / 16) / 256) * 256 + tid;
        const float4* B4 = (const float4*)(lB + (size_t)o * RANK);
        float4 b0 = B4[0], b1 = B4[1], b2 = B4[2], b3 = B4[3];
        union { u16 u[32]; uint4 q[4]; } ob;
        ob.u[0] = bf16bits(b0.x); ob.u[1] = bf16bits(b0.y); ob.u[2] = bf16bits(b0.z); ob.u[3] = bf16bits(b0.w);
        ob.u[4] = bf16bits(b1.x); ob.u[5] = bf16bits(b1.y); ob.u[6] = bf16bits(b1.z); ob.u[7] = bf16bits(b1.w);
        ob.u[8] = bf16bits(b2.x); ob.u[9] = bf16bits(b2.y); ob.u[10] = bf16bits(b2.z); ob.u[11] = bf16bits(b2.w);
        ob.u[12] = bf16bits(b3.x); ob.u[13] = bf16bits(b3.y); ob.u[14] = bf16bits(b3.z); ob.u[15] = bf16bits(b3.w);
#pragma unroll
        for (int k = 16; k < 32; k++) ob.u[k] = 0;
        uint4* dst = (uint4*)(Bl + (size_t)o * 32);
        dst[0] = ob.q[0]; dst[1] = ob.q[1]; dst[2] = ob.q[2]; dst[3] = ob.q[3];
    } else {
        const int r = b - (TOKENS + OUT_F * (IN_F / 16) / 256 + OUT_F / 256);
        const float4* A4 = (const float4*)(lA + (size_t)r * IN_F);
        float4 v[4];
#pragma unroll
        for (int j = 0; j < 4; j++) v[j] = A4[tid * 4 + j];

        float m = 0.f;
#pragma unroll
        for (int j = 0; j < 4; j++)
            m = fmaxf(m, fmaxf(fmaxf(fabsf(v[j].x), fabsf(v[j].y)),
                               fmaxf(fabsf(v[j].z), fabsf(v[j].w))));
#pragma unroll
        for (int off = 32; off > 0; off >>= 1) m = fmaxf(m, __shfl_down(m, off));
        if (lane == 0) rm[wv] = m;
        __syncthreads();
        float M = fmaxf(fmaxf(rm[0], rm[1]), fmaxf(rm[2], rm[3]));
        M = fmaxf(M, 1e-20f);
        if (tid == 0) aScale[r] = M / 127.0f;

        float inv = 127.0f / M;
        uint4 o;
        o.x = quant4(v[0].x, v[0].y, v[0].z, v[0].w, inv);
        o.y = quant4(v[1].x, v[1].y, v[1].z, v[1].w, inv);
        o.z = quant4(v[2].x, v[2].y, v[2].z, v[2].w, inv);
        o.w = quant4(v[3].x, v[3].y, v[3].z, v[3].w, inv);
        *(uint4*)(Aq + (size_t)r * IN_F + tid * 16) = o;
    }
}

// ---- y = x * A^T via i8 MFMA: 16 tokens per block, 4 waves K-split + LDS reduce ----
__global__ __launch_bounds__(256) void k_lora_y(const signed char* __restrict__ Xq,
                                                const signed char* __restrict__ Aq,
                                                const float* __restrict__ sArr,
                                                const float* __restrict__ aScale,
                                                u16* __restrict__ ypad) {
    __shared__ i32x4 red[4][64];
    const int tid = threadIdx.x;
    const int lane = tid & 63;
    const int wv = tid >> 6;
    const int t0 = blockIdx.x * 16;
    const int fr = lane & 15;
    const int q16 = (lane >> 4) * 16;

    i32x4 acc = {};
    const signed char* xrow = Xq + (size_t)(t0 + fr) * IN_F + wv * 1024 + q16;
    const signed char* arow = Aq + (size_t)fr * IN_F + wv * 1024 + q16;
#pragma unroll
    for (int k0 = 0; k0 < 1024; k0 += 64) {
        i32x4 af = *(const i32x4*)(xrow + k0);
        i32x4 bf = *(const i32x4*)(arow + k0);
        acc = __builtin_amdgcn_mfma_i32_16x16x64_i8(af, bf, acc, 0, 0, 0);
    }
    red[wv][lane] = acc;
    __syncthreads();
    if (wv == 0) {
        i32x4 s0 = red[0][lane], s1 = red[1][lane], s2 = red[2][lane], s3 = red[3][lane];
        const int c0 = lane & 15;
        const int r0 = (lane >> 4) * 4;
        float asc = aScale[c0];
#pragma unroll
        for (int r = 0; r < 4; r++) {
            int t = t0 + r0 + r;
            float y = sArr[t] * asc * (float)(s0[r] + s1[r] + s2[r] + s3[r]);
            ypad[(size_t)t * 32 + c0] = bf16bits(y);
            ypad[(size_t)t * 32 + 16 + c0] = 0;
        }
    }
}

// ===================== 256x256 8-phase i8 GEMM =====================
// LDS: buf d in {0,1} at d*65536; A half h at +h*16384; B at +32768 + h*16384.
// A half h covers tile rows {(b<<7)+(h<<6)+r63}; B half h covers cols {(b<<6)+(h<<5)+r31}.
// XOR slot swizzle (slot ^= rho&7) applied pre-swizzled-source + swizzled-read (rule 21).

#define STAGE_A(srcTile, h, dbuf)                                              \
    {                                                                          \
        _Pragma("unroll")                                                      \
        for (int j = 0; j < 2; j++) {                                          \
            int c = j * 512 + tid;                                             \
            int rho = c >> 3;                                                  \
            int sl = (c & 7) ^ (rho & 7);                                      \
            int trow = ((rho >> 6) << 7) + ((h) << 6) + (rho & 63);            \
            GLDS16(Xq + (size_t)(m0 + trow) * IN_F + (srcTile) * BK + sl * 16, \
                   smem + (dbuf) * 65536 + (h) * 16384 + j * 8192 + wvb);      \
        }                                                                      \
    }

#define STAGE_B(srcTile, h, dbuf)                                              \
    {                                                                          \
        _Pragma("unroll")                                                      \
        for (int j = 0; j < 2; j++) {                                          \
            int c = j * 512 + tid;                                             \
            int rho = c >> 3;                                                  \
            int sl = (c & 7) ^ (rho & 7);                                      \
            int tcol = ((rho >> 5) << 6) + ((h) << 5) + (rho & 31);            \
            GLDS16(Wq + (size_t)(n0 + tcol) * IN_F + (srcTile) * BK + sl * 16, \
                   smem + (dbuf) * 65536 + 32768 + (h) * 16384 + j * 8192 + wvb); \
        }                                                                      \
    }

#define READ_A(h)                                                              \
    {                                                                          \
        _Pragma("unroll")                                                      \
        for (int ml = 0; ml < 4; ml++) {                                       \
            _Pragma("unroll")                                                  \
            for (int ks = 0; ks < 2; ks++) {                                   \
                int rho = wmi * 64 + ml * 16 + fr;                             \
                int s = (ks * 4 + qs) ^ (rho & 7);                             \
                af[ml][ks] = *(const i32x4*)(smem + d * 65536 + (h) * 16384 +  \
                                             rho * 128 + s * 16);              \
            }                                                                  \
        }                                                                      \
    }

#define READ_B(hb)                                                             \
    {                                                                          \
        _Pragma("unroll")                                                      \
        for (int nl = 0; nl < 2; nl++) {                                       \
            _Pragma("unroll")                                                  \
            for (int ks = 0; ks < 2; ks++) {                                   \
                int rho = wni * 32 + nl * 16 + fr;                             \
                int s = (ks * 4 + qs) ^ (rho & 7);                             \
                bf[(hb) * 2 + nl][ks] = *(const i32x4*)(smem + d * 65536 +     \
                    32768 + (hb) * 16384 + rho * 128 + s * 16);                \
            }                                                                  \
        }                                                                      \
    }

#define MFMA_PHASE(ha, hb)                                                     \
    {                                                                          \
        __builtin_amdgcn_s_setprio(1);                                         \
        _Pragma("unroll")                                                      \
        for (int ml = 0; ml < 4; ml++) {                                       \
            _Pragma("unroll")                                                  \
            for (int nl = 0; nl < 2; nl++) {                                   \
                _Pragma("unroll")                                              \
                for (int ks = 0; ks < 2; ks++)                                 \
                    acc[(ha) * 4 + ml][(hb) * 2 + nl] =                        \
                        __builtin_amdgcn_mfma_i32_16x16x64_i8(                 \
                            af[ml][ks], bf[(hb) * 2 + nl][ks],                 \
                            acc[(ha) * 4 + ml][(hb) * 2 + nl], 0, 0, 0);       \
            }                                                                  \
        }                                                                      \
        __builtin_amdgcn_s_setprio(0);                                         \
    }

__global__ __launch_bounds__(512, 2) void k_gemm_i8(const signed char* __restrict__ Xq,
                                                    const signed char* __restrict__ Wq,
                                                    const float* __restrict__ sArr,
                                                    const float* __restrict__ SArr,
                                                    const float* __restrict__ alpha,
                                                    const float* __restrict__ mu,
                                                    const float* __restrict__ bias,
                                                    const u16* __restrict__ ypad,
                                                    const u16* __restrict__ Bl,
                                                    float* __restrict__ out) {
    __shared__ unsigned char smem[131072];

    const int tid = threadIdx.x;
    const int lane = tid & 63;
    const int wid = tid >> 6;        // 0..7
    const int wmi = wid >> 2;        // 0..1 : wave M index (128 rows each)
    const int wni = wid & 3;         // 0..3 : wave N index (64 cols each)
    const int fr = lane & 15;
    const int qs = lane >> 4;        // 0..3 : 16B k-slot
    const int wvb = wid * 1024;

    // bijective XCD-chunk swizzle (512 % 8 == 0)
    int id = blockIdx.x;
    int swz = (id & 7) * 64 + (id >> 3);
    const int m0 = (swz >> 4) * BM;  // token tile (0..31)
    const int n0 = (swz & 15) * BN;  // outfeat tile (0..15)

    i32x4 acc[8][4] = {};
    i32x4 af[4][2], bf[4][2];

    // prologue FIFO: Ah0(0), Bh0(0), Bh1(0), Ah1(0), Ah0(1), Bh0(1)
    STAGE_A(0, 0, 0); STAGE_B(0, 0, 0); STAGE_B(0, 1, 0); STAGE_A(0, 1, 0);
    STAGE_A(1, 0, 1); STAGE_B(1, 0, 1);
    VMCNT8; BARRIER;

#pragma unroll 2
    for (int t = 0; t < NT; ++t) {
        const int d = t & 1;
        const int dn = d ^ 1;
        const int tp1 = (t + 1 < NT) ? (t + 1) : (NT - 1);
        const int tp2 = (t + 2 < NT) ? (t + 2) : (NT - 1);
        // P0 (A half0, B half0)
        READ_A(0); READ_B(0);
        STAGE_B(tp1, 1, dn);            // Bh1(t+1)
        VMCNT8; BARRIER;                // guards Bh1(t) for P1 reads
        MFMA_PHASE(0, 0);
        BARRIER;
        // P1 (A half0, B half1)
        READ_B(1);
        STAGE_A(tp1, 1, dn);            // Ah1(t+1)
        VMCNT8; BARRIER;                // guards Ah1(t) for P2 reads
        MFMA_PHASE(0, 1);
        BARRIER;
        // P2 (A half1, B half1)
        READ_A(1);
        STAGE_A(tp2, 0, d);             // Ah0(t+2) into buf[t&1] (region free after P0)
        BARRIER;
        MFMA_PHASE(1, 1);
        BARRIER;
        // P3 (A half1, B half0)
        STAGE_B(tp2, 0, d);             // Bh0(t+2)
        VMCNT8; BARRIER;                // guards Ah0(t+1),Bh0(t+1) for next P0
        MFMA_PHASE(1, 0);
        BARRIER;
    }

    // ---- epilogue: drain, stage lora operands, convert, lora MFMA, store ----
    VMCNT0; BARRIER;
#pragma unroll
    for (int j = 0; j < 2; j++) {
        int c = j * 512 + tid;
        int row = c >> 2;
        int sl = ((c & 3) ^ swz4(row)) << 4;
        GLDS16((const unsigned char*)ypad + (size_t)(m0 + row) * 64 + sl,
               smem + j * 8192 + wvb);
        GLDS16((const unsigned char*)Bl + (size_t)(n0 + row) * 64 + sl,
               smem + 16384 + j * 8192 + wvb);
    }

    const int r0 = qs * 4;
    const int c0 = fr;
    float av[4], mv[4], bv[4];
#pragma unroll
    for (int nt = 0; nt < 4; nt++) {
        int col = n0 + wni * 64 + nt * 16 + c0;
        av[nt] = alpha[col]; mv[nt] = mu[col]; bv[nt] = bias[col];
    }
    f32x4 facc[8][4];
#pragma unroll
    for (int mt = 0; mt < 8; mt++) {
        int rb = m0 + wmi * 128 + mt * 16 + r0;
        f32x4 sv = *(const f32x4*)(sArr + rb);
        f32x4 Sv = *(const f32x4*)(SArr + rb);
#pragma unroll
        for (int nt = 0; nt < 4; nt++)
#pragma unroll
            for (int r = 0; r < 4; r++)
                facc[mt][nt][r] = av[nt] * sv[r] * (float)acc[mt][nt][r] + fmaf(mv[nt], Sv[r], bv[nt]);
    }

    VMCNT0; BARRIER;
    bf16x8 yf[8], blf[4];
#pragma unroll
    for (int mt = 0; mt < 8; mt++) {
        int row = wmi * 128 + mt * 16 + fr;
        int s = (qs ^ swz4(row)) << 4;
        yf[mt] = *(const bf16x8*)(smem + row * 64 + s);
    }
#pragma unroll
    for (int nt = 0; nt < 4; nt++) {
        int row = wni * 64 + nt * 16 + fr;
        int s = (qs ^ swz4(row)) << 4;
        blf[nt] = *(const bf16x8*)(smem + 16384 + row * 64 + s);
    }
#pragma unroll
    for (int mt = 0; mt < 8; mt++)
#pragma unroll
        for (int nt = 0; nt < 4; nt++)
            facc[mt][nt] = __builtin_amdgcn_mfma_f32_16x16x32_bf16(yf[mt], blf[nt], facc[mt][nt], 0, 0, 0);

#pragma unroll
    for (int mt = 0; mt < 8; mt++) {
        int row = m0 + wmi * 128 + mt * 16 + r0;
#pragma unroll
        for (int nt = 0; nt < 4; nt++) {
            int col = n0 + wni * 64 + nt * 16 + c0;
            float* op = out + (size_t)row * OUT_F + col;
#pragma unroll
            for (int r = 0; r < 4; r++)
                op[(size_t)r * OUT_F] = facc[mt][nt][r];
        }
    }
}

extern "C" void kernel_launch(void* const* d_in, const int* in_sizes, int n_in,
                              void* d_out, int out_size, void* d_ws, size_t ws_size,
                              hipStream_t stream) {
    const float* x      = (const float*)d_in[0];
    const int*   packed = (const int*)d_in[1];
    const float* alpha  = (const float*)d_in[2];
    const float* mu     = (const float*)d_in[3];
    const float* bias   = (const float*)d_in[4];
    const float* lA     = (const float*)d_in[5];
    const float* lB     = (const float*)d_in[6];
    float* out = (float*)d_out;

    char* p = (char*)d_ws;
    signed char* Wq = (signed char*)p;             p += (size_t)OUT_F * IN_F;        // 16 MiB
    signed char* Xq = (signed char*)p;             p += (size_t)TOKENS * IN_F;       // 32 MiB
    float* sArr = (float*)p;                       p += (size_t)TOKENS * 4;
    float* SArr = (float*)p;                       p += (size_t)TOKENS * 4;
    u16* ypad = (u16*)p;                           p += (size_t)TOKENS * 32 * 2;     // 512 KiB
    u16* Bl = (u16*)p;                             p += (size_t)OUT_F * 32 * 2;      // 256 KiB
    signed char* Aq = (signed char*)p;             p += (size_t)RANK * IN_F;         // 64 KiB
    float* aScale = (float*)p;                     p += RANK * 4;

    const int prep_blocks = TOKENS + OUT_F * (IN_F / 16) / 256 + OUT_F / 256 + RANK; // 12320
    k_prep<<<dim3(prep_blocks), dim3(256), 0, stream>>>(x, packed, lA, lB, Xq, sArr, SArr, Wq, Bl, Aq, aScale);
    k_lora_y<<<dim3(TOKENS / 16), dim3(256), 0, stream>>>(Xq, Aq, sArr, aScale, ypad);

    k_gemm_i8<<<dim3(512), dim3(512), 0, stream>>>(Xq, Wq, sArr, SArr, alpha, mu, bias, ypad, Bl, out);
}

// Round 4
// 363.135 us; speedup vs baseline: 1.1321x; 1.0009x over previous
//
#include <hip/hip_runtime.h>
#include <stdint.h>

#define IN_F   4096
#define OUT_F  4096
#define TOKENS 8192
#define RANK   16

#define BM 256
#define BN 256
#define BK 128            // i8 elements per K-tile = 128B rows
#define NT (IN_F / BK)    // 32 K-tiles

typedef unsigned short u16;
typedef __attribute__((ext_vector_type(8))) short bf16x8;
typedef __attribute__((ext_vector_type(4))) float f32x4;
typedef __attribute__((ext_vector_type(4))) int i32x4;

// async global->LDS, 16B/lane; LDS dest = wave-uniform base, HW adds lane*16
#define GLDS16(g, l) __builtin_amdgcn_global_load_lds( \
    (__attribute__((address_space(1))) void*)(g),      \
    (__attribute__((address_space(3))) void*)(l), 16, 0, 0)

#define MEMFENCE asm volatile("" ::: "memory")
#define BARRIER  do { MEMFENCE; __builtin_amdgcn_s_barrier(); MEMFENCE; } while (0)
#define VMCNT8   asm volatile("s_waitcnt vmcnt(8)" ::: "memory")
#define VMCNT0   asm volatile("s_waitcnt vmcnt(0)" ::: "memory")

__device__ __forceinline__ int swz4(int row) { return (row & 3) ^ ((row >> 2) & 1); }

__device__ __forceinline__ u16 bf16bits(float f) {
    unsigned int u = __builtin_bit_cast(unsigned int, f);
    unsigned int lsb = (u >> 16) & 1u;
    u += 0x7fffu + lsb;
    return (u16)(u >> 16);
}

__device__ __forceinline__ unsigned int quant4(float a, float b, float c, float d, float inv) {
    int qa = __float2int_rn(a * inv); qa = max(-127, min(127, qa));
    int qb = __float2int_rn(b * inv); qb = max(-127, min(127, qb));
    int qc = __float2int_rn(c * inv); qc = max(-127, min(127, qc));
    int qd = __float2int_rn(d * inv); qd = max(-127, min(127, qd));
    return (qa & 255) | ((qb & 255) << 8) | ((qc & 255) << 16) | ((qd & 255) << 24);
}

// ---- fused prep: [0,TOKENS) token quant | next 4096 W-build | next 16 B-lora | last 16 A-quant
// X/A quant use COALESCED loads: thread t takes float4 index j*256+t (lane-contiguous
// 16B per instruction) instead of 4 consecutive float4s (64B/lane stride, 4x TA traffic).
__global__ __launch_bounds__(256) void k_prep(const float* __restrict__ X,
                                              const int* __restrict__ packed,
                                              const float* __restrict__ lA,
                                              const float* __restrict__ lB,
                                              signed char* __restrict__ Xq,
                                              float* __restrict__ sArr,
                                              float* __restrict__ SArr,
                                              signed char* __restrict__ Wq,
                                              u16* __restrict__ Bl,
                                              signed char* __restrict__ Aq,
                                              float* __restrict__ aScale) {
    __shared__ float rs[4], rm[4];
    const int b = blockIdx.x;
    const int tid = threadIdx.x;
    const int lane = tid & 63;
    const int wv = tid >> 6;

    if (b < TOKENS) {
        const int t = b;
        const float4* X4 = (const float4*)(X + (size_t)t * IN_F);
        float4 v[4];
#pragma unroll
        for (int j = 0; j < 4; j++) v[j] = X4[j * 256 + tid];

        float s = 0.f, m = 0.f;
#pragma unroll
        for (int j = 0; j < 4; j++) {
            s += v[j].x + v[j].y + v[j].z + v[j].w;
            m = fmaxf(m, fmaxf(fmaxf(fabsf(v[j].x), fabsf(v[j].y)),
                               fmaxf(fabsf(v[j].z), fabsf(v[j].w))));
        }
#pragma unroll
        for (int off = 32; off > 0; off >>= 1) {
            s += __shfl_down(s, off);
            m = fmaxf(m, __shfl_down(m, off));
        }
        if (lane == 0) { rs[wv] = s; rm[wv] = m; }
        __syncthreads();
        float S = rs[0] + rs[1] + rs[2] + rs[3];
        float M = fmaxf(fmaxf(rm[0], rm[1]), fmaxf(rm[2], rm[3]));
        M = fmaxf(M, 1e-20f);
        if (tid == 0) { SArr[t] = S; sArr[t] = M / 127.0f; }

        float inv = 127.0f / M;
        unsigned int* Xq32 = (unsigned int*)(Xq + (size_t)t * IN_F);
#pragma unroll
        for (int j = 0; j < 4; j++)
            Xq32[j * 256 + tid] = quant4(v[j].x, v[j].y, v[j].z, v[j].w, inv);
    } else if (b < TOKENS + OUT_F * (IN_F / 16) / 256) {
        int idx = (b - TOKENS) * 256 + tid;
        int p = packed[idx];
        uint4 o;
        unsigned int w[4];
#pragma unroll
        for (int g = 0; g < 4; g++) {
            unsigned int word = 0;
#pragma unroll
            for (int j = 0; j < 4; j++) {
                int k = g * 4 + j;
                int bb = ((p >> (2 * k)) & 3) - 1;
                word |= (unsigned int)(bb & 255) << (8 * j);
            }
            w[g] = word;
        }
        o.x = w[0]; o.y = w[1]; o.z = w[2]; o.w = w[3];
        *(uint4*)(Wq + (size_t)idx * 16) = o;
    } else if (b < TOKENS + OUT_F * (IN_F / 16) / 256 + OUT_F / 256) {
        int o = (b - TOKENS - OUT_F * (IN_F / 16) / 256) * 256 + tid;
        const float4* B4 = (const float4*)(lB + (size_t)o * RANK);
        float4 b0 = B4[0], b1 = B4[1], b2 = B4[2], b3 = B4[3];
        union { u16 u[32]; uint4 q[4]; } ob;
        ob.u[0] = bf16bits(b0.x); ob.u[1] = bf16bits(b0.y); ob.u[2] = bf16bits(b0.z); ob.u[3] = bf16bits(b0.w);
        ob.u[4] = bf16bits(b1.x); ob.u[5] = bf16bits(b1.y); ob.u[6] = bf16bits(b1.z); ob.u[7] = bf16bits(b1.w);
        ob.u[8] = bf16bits(b2.x); ob.u[9] = bf16bits(b2.y); ob.u[10] = bf16bits(b2.z); ob.u[11] = bf16bits(b2.w);
        ob.u[12] = bf16bits(b3.x); ob.u[13] = bf16bits(b3.y); ob.u[14] = bf16bits(b3.z); ob.u[15] = bf16bits(b3.w);
#pragma unroll
        for (int k = 16; k < 32; k++) ob.u[k] = 0;
        uint4* dst = (uint4*)(Bl + (size_t)o * 32);
        dst[0] = ob.q[0]; dst[1] = ob.q[1]; dst[2] = ob.q[2]; dst[3] = ob.q[3];
    } else {
        const int r = b - (TOKENS + OUT_F * (IN_F / 16) / 256 + OUT_F / 256);
        const float4* A4 = (const float4*)(lA + (size_t)r * IN_F);
        float4 v[4];
#pragma unroll
        for (int j = 0; j < 4; j++) v[j] = A4[j * 256 + tid];

        float m = 0.f;
#pragma unroll
        for (int j = 0; j < 4; j++)
            m = fmaxf(m, fmaxf(fmaxf(fabsf(v[j].x), fabsf(v[j].y)),
                               fmaxf(fabsf(v[j].z), fabsf(v[j].w))));
#pragma unroll
        for (int off = 32; off > 0; off >>= 1) m = fmaxf(m, __shfl_down(m, off));
        if (lane == 0) rm[wv] = m;
        __syncthreads();
        float M = fmaxf(fmaxf(rm[0], rm[1]), fmaxf(rm[2], rm[3]));
        M = fmaxf(M, 1e-20f);
        if (tid == 0) aScale[r] = M / 127.0f;

        float inv = 127.0f / M;
        unsigned int* Aq32 = (unsigned int*)(Aq + (size_t)r * IN_F);
#pragma unroll
        for (int j = 0; j < 4; j++)
            Aq32[j * 256 + tid] = quant4(v[j].x, v[j].y, v[j].z, v[j].w, inv);
    }
}

// ---- y = x * A^T via i8 MFMA: 16 tokens per block, 4 waves K-split + LDS reduce ----
__global__ __launch_bounds__(256) void k_lora_y(const signed char* __restrict__ Xq,
                                                const signed char* __restrict__ Aq,
                                                const float* __restrict__ sArr,
                                                const float* __restrict__ aScale,
                                                u16* __restrict__ ypad) {
    __shared__ i32x4 red[4][64];
    const int tid = threadIdx.x;
    const int lane = tid & 63;
    const int wv = tid >> 6;
    const int t0 = blockIdx.x * 16;
    const int fr = lane & 15;
    const int q16 = (lane >> 4) * 16;

    i32x4 acc = {};
    const signed char* xrow = Xq + (size_t)(t0 + fr) * IN_F + wv * 1024 + q16;
    const signed char* arow = Aq + (size_t)fr * IN_F + wv * 1024 + q16;
#pragma unroll
    for (int k0 = 0; k0 < 1024; k0 += 64) {
        i32x4 af = *(const i32x4*)(xrow + k0);
        i32x4 bf = *(const i32x4*)(arow + k0);
        acc = __builtin_amdgcn_mfma_i32_16x16x64_i8(af, bf, acc, 0, 0, 0);
    }
    red[wv][lane] = acc;
    __syncthreads();
    if (wv == 0) {
        i32x4 s0 = red[0][lane], s1 = red[1][lane], s2 = red[2][lane], s3 = red[3][lane];
        const int c0 = lane & 15;
        const int r0 = (lane >> 4) * 4;
        float asc = aScale[c0];
#pragma unroll
        for (int r = 0; r < 4; r++) {
            int t = t0 + r0 + r;
            float y = sArr[t] * asc * (float)(s0[r] + s1[r] + s2[r] + s3[r]);
            ypad[(size_t)t * 32 + c0] = bf16bits(y);
            ypad[(size_t)t * 32 + 16 + c0] = 0;
        }
    }
}

// ===================== 256x256 8-phase i8 GEMM =====================
// LDS: buf d in {0,1} at d*65536; A half h at +h*16384; B at +32768 + h*16384.
// A half h covers tile rows {(b<<7)+(h<<6)+r63}; B half h covers cols {(b<<6)+(h<<5)+r31}.
// XOR slot swizzle (slot ^= rho&7) applied pre-swizzled-source + swizzled-read (rule 21).

#define STAGE_A(srcTile, h, dbuf)                                              \
    {                                                                          \
        _Pragma("unroll")                                                      \
        for (int j = 0; j < 2; j++) {                                          \
            int c = j * 512 + tid;                                             \
            int rho = c >> 3;                                                  \
            int sl = (c & 7) ^ (rho & 7);                                      \
            int trow = ((rho >> 6) << 7) + ((h) << 6) + (rho & 63);            \
            GLDS16(Xq + (size_t)(m0 + trow) * IN_F + (srcTile) * BK + sl * 16, \
                   smem + (dbuf) * 65536 + (h) * 16384 + j * 8192 + wvb);      \
        }                                                                      \
    }

#define STAGE_B(srcTile, h, dbuf)                                              \
    {                                                                          \
        _Pragma("unroll")                                                      \
        for (int j = 0; j < 2; j++) {                                          \
            int c = j * 512 + tid;                                             \
            int rho = c >> 3;                                                  \
            int sl = (c & 7) ^ (rho & 7);                                      \
            int tcol = ((rho >> 5) << 6) + ((h) << 5) + (rho & 31);            \
            GLDS16(Wq + (size_t)(n0 + tcol) * IN_F + (srcTile) * BK + sl * 16, \
                   smem + (dbuf) * 65536 + 32768 + (h) * 16384 + j * 8192 + wvb); \
        }                                                                      \
    }

#define READ_A(h)                                                              \
    {                                                                          \
        _Pragma("unroll")                                                      \
        for (int ml = 0; ml < 4; ml++) {                                       \
            _Pragma("unroll")                                                  \
            for (int ks = 0; ks < 2; ks++) {                                   \
                int rho = wmi * 64 + ml * 16 + fr;                             \
                int s = (ks * 4 + qs) ^ (rho & 7);                             \
                af[ml][ks] = *(const i32x4*)(smem + d * 65536 + (h) * 16384 +  \
                                             rho * 128 + s * 16);              \
            }                                                                  \
        }                                                                      \
    }

#define READ_B(hb)                                                             \
    {                                                                          \
        _Pragma("unroll")                                                      \
        for (int nl = 0; nl < 2; nl++) {                                       \
            _Pragma("unroll")                                                  \
            for (int ks = 0; ks < 2; ks++) {                                   \
                int rho = wni * 32 + nl * 16 + fr;                             \
                int s = (ks * 4 + qs) ^ (rho & 7);                             \
                bf[(hb) * 2 + nl][ks] = *(const i32x4*)(smem + d * 65536 +     \
                    32768 + (hb) * 16384 + rho * 128 + s * 16);                \
            }                                                                  \
        }                                                                      \
    }

#define MFMA_PHASE(ha, hb)                                                     \
    {                                                                          \
        __builtin_amdgcn_s_setprio(1);                                         \
        _Pragma("unroll")                                                      \
        for (int ml = 0; ml < 4; ml++) {                                       \
            _Pragma("unroll")                                                  \
            for (int nl = 0; nl < 2; nl++) {                                   \
                _Pragma("unroll")                                              \
                for (int ks = 0; ks < 2; ks++)                                 \
                    acc[(ha) * 4 + ml][(hb) * 2 + nl] =                        \
                        __builtin_amdgcn_mfma_i32_16x16x64_i8(                 \
                            af[ml][ks], bf[(hb) * 2 + nl][ks],                 \
                            acc[(ha) * 4 + ml][(hb) * 2 + nl], 0, 0, 0);       \
            }                                                                  \
        }                                                                      \
        __builtin_amdgcn_s_setprio(0);                                         \
    }

__global__ __launch_bounds__(512, 2) void k_gemm_i8(const signed char* __restrict__ Xq,
                                                    const signed char* __restrict__ Wq,
                                                    const float* __restrict__ sArr,
                                                    const float* __restrict__ SArr,
                                                    const float* __restrict__ alpha,
                                                    const float* __restrict__ mu,
                                                    const float* __restrict__ bias,
                                                    const u16* __restrict__ ypad,
                                                    const u16* __restrict__ Bl,
                                                    float* __restrict__ out) {
    __shared__ unsigned char smem[131072];

    const int tid = threadIdx.x;
    const int lane = tid & 63;
    const int wid = tid >> 6;        // 0..7
    const int wmi = wid >> 2;        // 0..1 : wave M index (128 rows each)
    const int wni = wid & 3;         // 0..3 : wave N index (64 cols each)
    const int fr = lane & 15;
    const int qs = lane >> 4;        // 0..3 : 16B k-slot
    const int wvb = wid * 1024;

    // bijective XCD-chunk swizzle (512 % 8 == 0)
    int id = blockIdx.x;
    int swz = (id & 7) * 64 + (id >> 3);
    const int m0 = (swz >> 4) * BM;  // token tile (0..31)
    const int n0 = (swz & 15) * BN;  // outfeat tile (0..15)

    i32x4 acc[8][4] = {};
    i32x4 af[4][2], bf[4][2];

    // prologue FIFO: Ah0(0), Bh0(0), Bh1(0), Ah1(0), Ah0(1), Bh0(1)
    STAGE_A(0, 0, 0); STAGE_B(0, 0, 0); STAGE_B(0, 1, 0); STAGE_A(0, 1, 0);
    STAGE_A(1, 0, 1); STAGE_B(1, 0, 1);
    VMCNT8; BARRIER;

#pragma unroll 2
    for (int t = 0; t < NT; ++t) {
        const int d = t & 1;
        const int dn = d ^ 1;
        const int tp1 = (t + 1 < NT) ? (t + 1) : (NT - 1);
        const int tp2 = (t + 2 < NT) ? (t + 2) : (NT - 1);
        // P0 (A half0, B half0)
        READ_A(0); READ_B(0);
        STAGE_B(tp1, 1, dn);            // Bh1(t+1)
        VMCNT8; BARRIER;                // guards Bh1(t) for P1 reads
        MFMA_PHASE(0, 0);
        BARRIER;
        // P1 (A half0, B half1)
        READ_B(1);
        STAGE_A(tp1, 1, dn);            // Ah1(t+1)
        VMCNT8; BARRIER;                // guards Ah1(t) for P2 reads
        MFMA_PHASE(0, 1);
        BARRIER;
        // P2 (A half1, B half1)
        READ_A(1);
        STAGE_A(tp2, 0, d);             // Ah0(t+2) into buf[t&1] (region free after P0)
        BARRIER;
        MFMA_PHASE(1, 1);
        BARRIER;
        // P3 (A half1, B half0)
        STAGE_B(tp2, 0, d);             // Bh0(t+2)
        VMCNT8; BARRIER;                // guards Ah0(t+1),Bh0(t+1) for next P0
        MFMA_PHASE(1, 0);
        BARRIER;
    }

    // ---- epilogue: drain, stage lora operands, convert, lora MFMA, store ----
    VMCNT0; BARRIER;
#pragma unroll
    for (int j = 0; j < 2; j++) {
        int c = j * 512 + tid;
        int row = c >> 2;
        int sl = ((c & 3) ^ swz4(row)) << 4;
        GLDS16((const unsigned char*)ypad + (size_t)(m0 + row) * 64 + sl,
               smem + j * 8192 + wvb);
        GLDS16((const unsigned char*)Bl + (size_t)(n0 + row) * 64 + sl,
               smem + 16384 + j * 8192 + wvb);
    }

    const int r0 = qs * 4;
    const int c0 = fr;
    float av[4], mv[4], bv[4];
#pragma unroll
    for (int nt = 0; nt < 4; nt++) {
        int col = n0 + wni * 64 + nt * 16 + c0;
        av[nt] = alpha[col]; mv[nt] = mu[col]; bv[nt] = bias[col];
    }
    f32x4 facc[8][4];
#pragma unroll
    for (int mt = 0; mt < 8; mt++) {
        int rb = m0 + wmi * 128 + mt * 16 + r0;
        f32x4 sv = *(const f32x4*)(sArr + rb);
        f32x4 Sv = *(const f32x4*)(SArr + rb);
#pragma unroll
        for (int nt = 0; nt < 4; nt++)
#pragma unroll
            for (int r = 0; r < 4; r++)
                facc[mt][nt][r] = av[nt] * sv[r] * (float)acc[mt][nt][r] + fmaf(mv[nt], Sv[r], bv[nt]);
    }

    VMCNT0; BARRIER;
    bf16x8 yf[8], blf[4];
#pragma unroll
    for (int mt = 0; mt < 8; mt++) {
        int row = wmi * 128 + mt * 16 + fr;
        int s = (qs ^ swz4(row)) << 4;
        yf[mt] = *(const bf16x8*)(smem + row * 64 + s);
    }
#pragma unroll
    for (int nt = 0; nt < 4; nt++) {
        int row = wni * 64 + nt * 16 + fr;
        int s = (qs ^ swz4(row)) << 4;
        blf[nt] = *(const bf16x8*)(smem + 16384 + row * 64 + s);
    }
#pragma unroll
    for (int mt = 0; mt < 8; mt++)
#pragma unroll
        for (int nt = 0; nt < 4; nt++)
            facc[mt][nt] = __builtin_amdgcn_mfma_f32_16x16x32_bf16(yf[mt], blf[nt], facc[mt][nt], 0, 0, 0);

#pragma unroll
    for (int mt = 0; mt < 8; mt++) {
        int row = m0 + wmi * 128 + mt * 16 + r0;
#pragma unroll
        for (int nt = 0; nt < 4; nt++) {
            int col = n0 + wni * 64 + nt * 16 + c0;
            float* op = out + (size_t)row * OUT_F + col;
#pragma unroll
            for (int r = 0; r < 4; r++)
                op[(size_t)r * OUT_F] = facc[mt][nt][r];
        }
    }
}

extern "C" void kernel_launch(void* const* d_in, const int* in_sizes, int n_in,
                              void* d_out, int out_size, void* d_ws, size_t ws_size,
                              hipStream_t stream) {
    const float* x      = (const float*)d_in[0];
    const int*   packed = (const int*)d_in[1];
    const float* alpha  = (const float*)d_in[2];
    const float* mu     = (const float*)d_in[3];
    const float* bias   = (const float*)d_in[4];
    const float* lA     = (const float*)d_in[5];
    const float* lB     = (const float*)d_in[6];
    float* out = (float*)d_out;

    char* p = (char*)d_ws;
    signed char* Wq = (signed char*)p;             p += (size_t)OUT_F * IN_F;        // 16 MiB
    signed char* Xq = (signed char*)p;             p += (size_t)TOKENS * IN_F;       // 32 MiB
    float* sArr = (float*)p;                       p += (size_t)TOKENS * 4;
    float* SArr = (float*)p;                       p += (size_t)TOKENS * 4;
    u16* ypad = (u16*)p;                           p += (size_t)TOKENS * 32 * 2;     // 512 KiB
    u16* Bl = (u16*)p;                             p += (size_t)OUT_F * 32 * 2;      // 256 KiB
    signed char* Aq = (signed char*)p;             p += (size_t)RANK * IN_F;         // 64 KiB
    float* aScale = (float*)p;                     p += RANK * 4;

    const int prep_blocks = TOKENS + OUT_F * (IN_F / 16) / 256 + OUT_F / 256 + RANK; // 12320
    k_prep<<<dim3(prep_blocks), dim3(256), 0, stream>>>(x, packed, lA, lB, Xq, sArr, SArr, Wq, Bl, Aq, aScale);
    k_lora_y<<<dim3(TOKENS / 16), dim3(256), 0, stream>>>(Xq, Aq, sArr, aScale, ypad);

    k_gemm_i8<<<dim3(512), dim3(512), 0, stream>>>(Xq, Wq, sArr, SArr, alpha, mu, bias, ypad, Bl, out);
}